// Round 10
// baseline (286.177 us; speedup 1.0000x reference)
//
#include <hip/hip_runtime.h>

// Depthwise separable 4x4 FIR blur (StyleGAN2 upfirdn2d, up=down=1, pad=(2,2)).
// x: [B,C,256,256] f32, kernel: [4,4] f32 separable, out: [B,C,257,257] f32.
//
// out[q] = H[q+1] + v1*H[q] + v2*H[q-1] + v3*H[q-2],  H[r][c] = sum_j w[j]*x[r][c+1-j]
//
// R10 = R8 (best, 235us: self-contained 4-row-group tasks, global sweep) +
// two fabric-locality levers:
//  (1) XCD-CHUNKED SWEEP (T1): blocks dispatch round-robin across 8 XCDs, so
//      R8's consecutive tasks landed on DIFFERENT XCDs — overlap rows (3 of 7
//      per task) were re-fetched through L3 instead of hitting the local L2,
//      and each XCD's controllers saw an 8-way-interleaved scatter. Here each
//      XCD sweeps its own contiguous 1/8 of the task list (local window ~4MB
//      = fits its private L2; per-XCD request stream is near-sequential).
//  (2) NT STORES: output is write-once — stream it past L2/L3 (avoids L3
//      write-in + evict double traffic on the fabric). R4's NT regression was
//      confounded with a depth-2 rotation change; clean A/B here.
// Everything else identical to R8 (~60 VGPR, 8 waves/SIMD, shfl halo).

#define IW 256
#define IH 256
#define OW 257
#define OH 257
#define NG 65            // row-group tasks per plane: 64 full (4 rows) + 1 (row 256)
#define NXCD 8
#define WPX 1024         // waves per XCD chunk (2048 blocks * 4 waves / 8 XCDs)

typedef float f4u __attribute__((vector_size(16), aligned(4)));

__device__ __forceinline__ float sbc(float v) {   // wave-uniform -> SGPR
    return __uint_as_float(__builtin_amdgcn_readfirstlane(__float_as_uint(v)));
}

__global__ __launch_bounds__(256) void blur_fir_kernel(
    const float* __restrict__ x,
    const float* __restrict__ k2d,
    float* __restrict__ out,
    int ntasks)
{
    const int lane = threadIdx.x & 63;
    const int wv   = threadIdx.x >> 6;

    // XCD-chunked task mapping: block b runs on XCD (b % 8) [dispatch RR].
    const int xcd   = blockIdx.x & (NXCD - 1);
    const int lb    = blockIdx.x >> 3;             // local block in XCD: 0..255
    const int lw    = (lb << 2) + wv;              // local wave in XCD: 0..1023
    const int chunk = (ntasks + NXCD - 1) >> 3;    // tasks per XCD
    const int tbeg  = xcd * chunk;
    const int tend  = min(tbeg + chunk, ntasks);

    const float w0 = sbc(k2d[0]);
    const float w1 = sbc(k2d[1]);
    const float w2 = sbc(k2d[2]);
    const float w3 = sbc(k2d[3]);
    const float inv = 1.0f / w0;
    const float v1 = sbc(k2d[4]  * inv);
    const float v2 = sbc(k2d[8]  * inv);
    const float v3 = sbc(k2d[12] * inv);

    const int   c0 = lane << 2;
    const float mL = (lane > 0)  ? 1.0f : 0.0f;
    const float mR = (lane < 63) ? 1.0f : 0.0f;
    const int   lm = (lane > 0)  ? lane - 1 : 0;
    const int   lp = (lane < 63) ? lane + 1 : 63;
    const bool last = (lane == 63);

    for (int t = tbeg + lw; t < tend; t += WPX) {
        const int plane = t / NG;                  // const div -> magic mul
        const int rg    = t - plane * NG;
        const float* xp = x + ((size_t)plane << 16);
        float* op = out + (size_t)plane * (OW * OH) + (size_t)(rg << 2) * OW + c0;

        auto loadraw = [&](int r) -> float4 {
            int rr = min(max(r, 0), IH - 1);       // clamp; OOB masked in hcomb
            return *(const float4*)(xp + (rr << 8) + c0);
        };
        auto hcomb = [&](float4 Bv, int r, float4& h, float& h4) {
            float rm = (r >= 0 && r < IH) ? 1.0f : 0.0f;
            float lx = __shfl(Bv.z, lm, 64) * mL;  // x[r][c0-2]
            float ly = __shfl(Bv.w, lm, 64) * mL;  // x[r][c0-1]
            float rv = __shfl(Bv.x, lp, 64) * mR;  // x[r][c0+4]
            h.x = w0 * Bv.y + w1 * Bv.x + w2 * ly   + w3 * lx;
            h.y = w0 * Bv.z + w1 * Bv.y + w2 * Bv.x + w3 * ly;
            h.z = w0 * Bv.w + w1 * Bv.z + w2 * Bv.y + w3 * Bv.x;
            h.w = w0 * rv   + w1 * Bv.w + w2 * Bv.z + w3 * Bv.y;
            h4  = w2 * Bv.w + w3 * Bv.z;           // out col 256 (lane 63 only)
            h.x *= rm; h.y *= rm; h.z *= rm; h.w *= rm; h4 *= rm;
        };
        auto vcomb = [&](float4 a, float4 b, float4 c, float4 d) -> float4 {
            float4 r;
            r.x = a.x + v1 * b.x + v2 * c.x + v3 * d.x;
            r.y = a.y + v1 * b.y + v2 * c.y + v3 * d.y;
            r.z = a.z + v1 * b.z + v2 * c.z + v3 * d.z;
            r.w = a.w + v1 * b.w + v2 * c.w + v3 * d.w;
            return r;
        };

        if (rg < 64) {
            const int rb = rg << 2;                // out rows rb..rb+3
            float4 G0 = loadraw(rb - 2), G1 = loadraw(rb - 1), G2 = loadraw(rb);
            float4 G3 = loadraw(rb + 1), G4 = loadraw(rb + 2), G5 = loadraw(rb + 3);
            float4 G6 = loadraw(rb + 4);

            float4 F0, F1, F2, F3, F4, F5, F6;
            float  s0, s1, s2, s3, s4, s5, s6;
            hcomb(G0, rb - 2, F0, s0);
            hcomb(G1, rb - 1, F1, s1);
            hcomb(G2, rb    , F2, s2);
            hcomb(G3, rb + 1, F3, s3);
            hcomb(G4, rb + 2, F4, s4);
            hcomb(G5, rb + 3, F5, s5);
            hcomb(G6, rb + 4, F6, s6);

            float4 R0 = vcomb(F3, F2, F1, F0);     // out row rb
            float4 R1 = vcomb(F4, F3, F2, F1);
            float4 R2 = vcomb(F5, F4, F3, F2);
            float4 R3 = vcomb(F6, F5, F4, F3);
            __builtin_nontemporal_store((f4u){R0.x, R0.y, R0.z, R0.w}, (f4u*)(op         ));
            __builtin_nontemporal_store((f4u){R1.x, R1.y, R1.z, R1.w}, (f4u*)(op +     OW));
            __builtin_nontemporal_store((f4u){R2.x, R2.y, R2.z, R2.w}, (f4u*)(op + 2 * OW));
            __builtin_nontemporal_store((f4u){R3.x, R3.y, R3.z, R3.w}, (f4u*)(op + 3 * OW));
            if (last) {
                __builtin_nontemporal_store(s3 + v1 * s2 + v2 * s1 + v3 * s0, op + 4);
                __builtin_nontemporal_store(s4 + v1 * s3 + v2 * s2 + v3 * s1, op + OW + 4);
                __builtin_nontemporal_store(s5 + v1 * s4 + v2 * s3 + v3 * s2, op + 2 * OW + 4);
                __builtin_nontemporal_store(s6 + v1 * s5 + v2 * s4 + v3 * s3, op + 3 * OW + 4);
            }
        } else {
            // out row 256: H[256]=H[257]=0 -> v2*H[255] + v3*H[254]
            float4 GA = loadraw(254), GB = loadraw(255);
            float4 FA, FB; float sA, sB;
            hcomb(GA, 254, FA, sA);
            hcomb(GB, 255, FB, sB);
            float4 R;
            R.x = v2 * FB.x + v3 * FA.x;
            R.y = v2 * FB.y + v3 * FA.y;
            R.z = v2 * FB.z + v3 * FA.z;
            R.w = v2 * FB.w + v3 * FA.w;
            __builtin_nontemporal_store((f4u){R.x, R.y, R.z, R.w}, (f4u*)op);
            if (last) __builtin_nontemporal_store(v2 * sB + v3 * sA, op + 4);
        }
    }
}

extern "C" void kernel_launch(void* const* d_in, const int* in_sizes, int n_in,
                              void* d_out, int out_size, void* d_ws, size_t ws_size,
                              hipStream_t stream) {
    const float* x   = (const float*)d_in[0];
    const float* k2d = (const float*)d_in[1];
    float* out = (float*)d_out;

    int nplanes = in_sizes[0] >> 16;               // B*C = 2048
    int ntasks  = nplanes * NG;                    // 133120 group tasks
    int nblocks = 2048;                            // 8192 waves = 1024/XCD

    blur_fir_kernel<<<nblocks, 256, 0, stream>>>(x, k2d, out, ntasks);
}

// Round 11
// 217.622 us; speedup vs baseline: 1.3150x; 1.3150x over previous
//
#include <hip/hip_runtime.h>

// Depthwise separable 4x4 FIR blur (StyleGAN2 upfirdn2d, up=down=1, pad=(2,2)).
// x: [B,C,256,256] f32, kernel: [4,4] f32 separable, out: [B,C,257,257] f32.
//
// out[q] = H[q+1] + v1*H[q] + v2*H[q-1] + v3*H[q-2],  H[r][c] = sum_j w[j]*x[r][c+1-j]
//
// R11: SWEEP + 1.0x READ AMPLIFICATION (block-cooperative LDS).
// R8 (best, 235us) moved 1.51 GB at the L2 interface (1.75x read amp from
// 7-rows-per-4-row task) = 6.4 TB/s L2-side — the apparent binding resource.
// R5/R7 had 1.0x amp but lost R8's global-sweep DRAM efficiency. This round
// combines them: task = (plane, 16-output-row group); the block's 4 waves
// cooperatively compute the 19 H-rows (each input row loaded ONCE from
// global into registers, H via shfl, H written to a 19-row LDS ring), sync,
// then each wave builds its 4 output rows from 7 LDS H-rows. Amplification
// 1.75x -> 1.19x; L2-side 1.51 -> 1.18 GB. Sweep retained: 2048 blocks
// stride 32768 tasks -> ~32MB instantaneous window, same as R8.
// LDS 19x260x4 = 19.8 KB -> exactly 8 blocks/CU = 32 waves/CU (full).
// Plain stores (NT regressed twice: R4, R10). No XCD chunking (R10: neutral).

#define IW 256
#define IH 256
#define OW 257
#define OH 257
#define HSTR 260          // LDS H-row stride in floats (1040B, 16B-aligned rows)
#define NSLOT 19          // H[a-2 .. a+16]

typedef float f4u __attribute__((vector_size(16), aligned(4)));

__device__ __forceinline__ float sbc(float v) {   // wave-uniform -> SGPR
    return __uint_as_float(__builtin_amdgcn_readfirstlane(__float_as_uint(v)));
}

__global__ __launch_bounds__(256) void blur_fir_kernel(
    const float* __restrict__ x,
    const float* __restrict__ k2d,
    float* __restrict__ out,
    int ntasks, int nstride)
{
    __shared__ float Hs[NSLOT * HSTR];             // 19.76 KB

    const int lane = threadIdx.x & 63;
    const int wv   = threadIdx.x >> 6;             // 0..3

    const float w0 = sbc(k2d[0]);
    const float w1 = sbc(k2d[1]);
    const float w2 = sbc(k2d[2]);
    const float w3 = sbc(k2d[3]);
    const float inv = 1.0f / w0;
    const float v1 = sbc(k2d[4]  * inv);
    const float v2 = sbc(k2d[8]  * inv);
    const float v3 = sbc(k2d[12] * inv);

    const int   c0 = lane << 2;                    // 4 cols per lane
    const float mL = (lane > 0)  ? 1.0f : 0.0f;
    const float mR = (lane < 63) ? 1.0f : 0.0f;
    const int   lm = (lane > 0)  ? lane - 1 : 0;
    const int   lp = (lane < 63) ? lane + 1 : 63;
    const bool last = (lane == 63);

    for (int t = blockIdx.x; t < ntasks; t += nstride) {
        const int plane = t >> 4;                  // 16 groups per plane
        const int rg    = t & 15;
        const int a     = rg << 4;                 // first output row of group
        const float* xp = x + ((size_t)plane << 16);

        __syncthreads();                           // prev iteration done reading Hs

        // Phase 1: H slots j = wv, wv+4, ... (<19); slot j = H[a-2+j].
        // Each input row loaded ONCE (one float4/lane), halo via shfl.
        #pragma unroll
        for (int j = wv; j < NSLOT; j += 4) {
            const int r = a - 2 + j;
            int rr = min(max(r, 0), IH - 1);       // clamp; mask below
            float4 Bv = *(const float4*)(xp + (rr << 8) + c0);
            float rm = (r >= 0 && r < IH) ? 1.0f : 0.0f;
            float lx = __shfl(Bv.z, lm, 64) * mL;  // x[r][c0-2]
            float ly = __shfl(Bv.w, lm, 64) * mL;  // x[r][c0-1]
            float rv = __shfl(Bv.x, lp, 64) * mR;  // x[r][c0+4]
            float4 h;
            h.x = w0 * Bv.y + w1 * Bv.x + w2 * ly   + w3 * lx;
            h.y = w0 * Bv.z + w1 * Bv.y + w2 * Bv.x + w3 * ly;
            h.z = w0 * Bv.w + w1 * Bv.z + w2 * Bv.y + w3 * Bv.x;
            h.w = w0 * rv   + w1 * Bv.w + w2 * Bv.z + w3 * Bv.y;
            float h4 = (w2 * Bv.w + w3 * Bv.z) * rm;   // col 256 (lane 63)
            h.x *= rm; h.y *= rm; h.z *= rm; h.w *= rm;
            float* hp = Hs + j * HSTR;
            *(float4*)(hp + c0) = h;               // 16B-aligned, conflict-free
            if (last) hp[256] = h4;
        }
        __syncthreads();

        // Phase 2: wave wv -> output rows a+4wv .. a+4wv+3 from slots 4wv..4wv+6.
        const int j0 = wv << 2;
        const float* hb = Hs + j0 * HSTR + c0;
        float4 h0 = *(const float4*)(hb           );
        float4 h1 = *(const float4*)(hb +     HSTR);
        float4 h2 = *(const float4*)(hb + 2 * HSTR);
        float4 h3 = *(const float4*)(hb + 3 * HSTR);
        float4 h4 = *(const float4*)(hb + 4 * HSTR);
        float4 h5 = *(const float4*)(hb + 5 * HSTR);
        float4 h6 = *(const float4*)(hb + 6 * HSTR);

        auto vcomb = [&](float4 A, float4 B, float4 C, float4 D) -> float4 {
            float4 r;
            r.x = A.x + v1 * B.x + v2 * C.x + v3 * D.x;
            r.y = A.y + v1 * B.y + v2 * C.y + v3 * D.y;
            r.z = A.z + v1 * B.z + v2 * C.z + v3 * D.z;
            r.w = A.w + v1 * B.w + v2 * C.w + v3 * D.w;
            return r;
        };

        float* op = out + (size_t)plane * (OW * OH)
                        + (size_t)(a + (wv << 2)) * OW + c0;
        float4 R0 = vcomb(h3, h2, h1, h0);         // row a+4wv
        float4 R1 = vcomb(h4, h3, h2, h1);
        float4 R2 = vcomb(h5, h4, h3, h2);
        float4 R3 = vcomb(h6, h5, h4, h3);
        *(f4u*)(op         ) = (f4u){R0.x, R0.y, R0.z, R0.w};
        *(f4u*)(op +     OW) = (f4u){R1.x, R1.y, R1.z, R1.w};
        *(f4u*)(op + 2 * OW) = (f4u){R2.x, R2.y, R2.z, R2.w};
        *(f4u*)(op + 3 * OW) = (f4u){R3.x, R3.y, R3.z, R3.w};
        if (last) {
            const float* sp = Hs + j0 * HSTR + 256;
            float s0 = sp[0],        s1 = sp[HSTR],     s2 = sp[2 * HSTR];
            float s3 = sp[3 * HSTR], s4 = sp[4 * HSTR], s5 = sp[5 * HSTR];
            float s6 = sp[6 * HSTR];
            op[4]          = s3 + v1 * s2 + v2 * s1 + v3 * s0;
            op[OW + 4]     = s4 + v1 * s3 + v2 * s2 + v3 * s1;
            op[2 * OW + 4] = s5 + v1 * s4 + v2 * s3 + v3 * s2;
            op[3 * OW + 4] = s6 + v1 * s5 + v2 * s4 + v3 * s3;
        }

        // Output row 256 (only group 15, wave 3): H[256]=H[257]=0.
        if (rg == 15 && wv == 3) {
            float4 Hm2 = *(const float4*)(Hs + 16 * HSTR + c0);  // H[254]
            float4 Hm1 = *(const float4*)(Hs + 17 * HSTR + c0);  // H[255]
            float4 R;
            R.x = v2 * Hm1.x + v3 * Hm2.x;
            R.y = v2 * Hm1.y + v3 * Hm2.y;
            R.z = v2 * Hm1.z + v3 * Hm2.z;
            R.w = v2 * Hm1.w + v3 * Hm2.w;
            *(f4u*)(op + 4 * OW) = (f4u){R.x, R.y, R.z, R.w};
            if (last)
                op[4 * OW + 4] = v2 * Hs[17 * HSTR + 256] + v3 * Hs[16 * HSTR + 256];
        }
    }
}

extern "C" void kernel_launch(void* const* d_in, const int* in_sizes, int n_in,
                              void* d_out, int out_size, void* d_ws, size_t ws_size,
                              hipStream_t stream) {
    const float* x   = (const float*)d_in[0];
    const float* k2d = (const float*)d_in[1];
    float* out = (float*)d_out;

    int nplanes = in_sizes[0] >> 16;               // B*C = 2048
    int ntasks  = nplanes * 16;                    // 32768 16-row group tasks
    int nblocks = 2048;                            // 16 tasks per block, exact

    blur_fir_kernel<<<nblocks, 256, 0, stream>>>(x, k2d, out, ntasks, nblocks);
}

// Round 12
// 210.593 us; speedup vs baseline: 1.3589x; 1.0334x over previous
//
#include <hip/hip_runtime.h>

// Depthwise separable 4x4 FIR blur (StyleGAN2 upfirdn2d, up=down=1, pad=(2,2)).
// x: [B,C,256,256] f32, kernel: [4,4] f32 separable, out: [B,C,257,257] f32.
//
// out[q] = H[q+1] + v1*H[q] + v2*H[q-1] + v3*H[q-2],  H[r][c] = sum_j w[j]*x[r][c+1-j]
//
// R12 = R11 (sweep + block-cooperative LDS, 217.6us) with 32-ROW GROUPS:
//   - read amplification 19/16=1.19x -> 35/32=1.094x (L2-side traffic -4.3%)
//   - barriers per output row halved
//   - 512-thread blocks (8 waves); LDS 35x260x4 = 36.4 KB -> 4 blocks/CU
//     x 8 waves = full 32 waves/CU (unchanged)
//   - sweep preserved: 1024 blocks stride 16384 tasks -> instantaneous window
//     = 1024 consecutive tasks = contiguous 128-plane (~33MB) chunk.
// Plain stores (NT regressed R4+R10). Shfl halo. Same conflict-free LDS layout.

#define IW 256
#define IH 256
#define OW 257
#define OH 257
#define HSTR 260          // LDS H-row stride in floats (1040B, 16B-aligned rows)
#define NSLOT 35          // H[a-2 .. a+32]

typedef float f4u __attribute__((vector_size(16), aligned(4)));

__device__ __forceinline__ float sbc(float v) {   // wave-uniform -> SGPR
    return __uint_as_float(__builtin_amdgcn_readfirstlane(__float_as_uint(v)));
}

__global__ __launch_bounds__(512) void blur_fir_kernel(
    const float* __restrict__ x,
    const float* __restrict__ k2d,
    float* __restrict__ out,
    int ntasks, int nstride)
{
    __shared__ float Hs[NSLOT * HSTR];             // 36.4 KB

    const int lane = threadIdx.x & 63;
    const int wv   = threadIdx.x >> 6;             // 0..7

    const float w0 = sbc(k2d[0]);
    const float w1 = sbc(k2d[1]);
    const float w2 = sbc(k2d[2]);
    const float w3 = sbc(k2d[3]);
    const float inv = 1.0f / w0;
    const float v1 = sbc(k2d[4]  * inv);
    const float v2 = sbc(k2d[8]  * inv);
    const float v3 = sbc(k2d[12] * inv);

    const int   c0 = lane << 2;                    // 4 cols per lane
    const float mL = (lane > 0)  ? 1.0f : 0.0f;
    const float mR = (lane < 63) ? 1.0f : 0.0f;
    const int   lm = (lane > 0)  ? lane - 1 : 0;
    const int   lp = (lane < 63) ? lane + 1 : 63;
    const bool last = (lane == 63);

    for (int t = blockIdx.x; t < ntasks; t += nstride) {
        const int plane = t >> 3;                  // 8 groups per plane
        const int rg    = t & 7;
        const int a     = rg << 5;                 // first output row of group
        const float* xp = x + ((size_t)plane << 16);

        __syncthreads();                           // prev iteration done reading Hs

        // Phase 1: H slots j = wv, wv+8, ... (<35); slot j = H[a-2+j].
        // Each input row loaded ONCE (one float4/lane), halo via shfl.
        #pragma unroll
        for (int j = wv; j < NSLOT; j += 8) {
            const int r = a - 2 + j;
            int rr = min(max(r, 0), IH - 1);       // clamp; mask below
            float4 Bv = *(const float4*)(xp + (rr << 8) + c0);
            float rm = (r >= 0 && r < IH) ? 1.0f : 0.0f;
            float lx = __shfl(Bv.z, lm, 64) * mL;  // x[r][c0-2]
            float ly = __shfl(Bv.w, lm, 64) * mL;  // x[r][c0-1]
            float rv = __shfl(Bv.x, lp, 64) * mR;  // x[r][c0+4]
            float4 h;
            h.x = w0 * Bv.y + w1 * Bv.x + w2 * ly   + w3 * lx;
            h.y = w0 * Bv.z + w1 * Bv.y + w2 * Bv.x + w3 * ly;
            h.z = w0 * Bv.w + w1 * Bv.z + w2 * Bv.y + w3 * Bv.x;
            h.w = w0 * rv   + w1 * Bv.w + w2 * Bv.z + w3 * Bv.y;
            float h4 = (w2 * Bv.w + w3 * Bv.z) * rm;   // col 256 (lane 63)
            h.x *= rm; h.y *= rm; h.z *= rm; h.w *= rm;
            float* hp = Hs + j * HSTR;
            *(float4*)(hp + c0) = h;               // 16B-aligned, conflict-free
            if (last) hp[256] = h4;
        }
        __syncthreads();

        // Phase 2: wave wv -> output rows a+4wv .. a+4wv+3 from slots 4wv..4wv+6.
        const int j0 = wv << 2;
        const float* hb = Hs + j0 * HSTR + c0;
        float4 h0 = *(const float4*)(hb           );
        float4 h1 = *(const float4*)(hb +     HSTR);
        float4 h2 = *(const float4*)(hb + 2 * HSTR);
        float4 h3 = *(const float4*)(hb + 3 * HSTR);
        float4 h4 = *(const float4*)(hb + 4 * HSTR);
        float4 h5 = *(const float4*)(hb + 5 * HSTR);
        float4 h6 = *(const float4*)(hb + 6 * HSTR);

        auto vcomb = [&](float4 A, float4 B, float4 C, float4 D) -> float4 {
            float4 r;
            r.x = A.x + v1 * B.x + v2 * C.x + v3 * D.x;
            r.y = A.y + v1 * B.y + v2 * C.y + v3 * D.y;
            r.z = A.z + v1 * B.z + v2 * C.z + v3 * D.z;
            r.w = A.w + v1 * B.w + v2 * C.w + v3 * D.w;
            return r;
        };

        float* op = out + (size_t)plane * (OW * OH)
                        + (size_t)(a + (wv << 2)) * OW + c0;
        float4 R0 = vcomb(h3, h2, h1, h0);         // row a+4wv
        float4 R1 = vcomb(h4, h3, h2, h1);
        float4 R2 = vcomb(h5, h4, h3, h2);
        float4 R3 = vcomb(h6, h5, h4, h3);
        *(f4u*)(op         ) = (f4u){R0.x, R0.y, R0.z, R0.w};
        *(f4u*)(op +     OW) = (f4u){R1.x, R1.y, R1.z, R1.w};
        *(f4u*)(op + 2 * OW) = (f4u){R2.x, R2.y, R2.z, R2.w};
        *(f4u*)(op + 3 * OW) = (f4u){R3.x, R3.y, R3.z, R3.w};
        if (last) {
            const float* sp = Hs + j0 * HSTR + 256;
            float s0 = sp[0],        s1 = sp[HSTR],     s2 = sp[2 * HSTR];
            float s3 = sp[3 * HSTR], s4 = sp[4 * HSTR], s5 = sp[5 * HSTR];
            float s6 = sp[6 * HSTR];
            op[4]          = s3 + v1 * s2 + v2 * s1 + v3 * s0;
            op[OW + 4]     = s4 + v1 * s3 + v2 * s2 + v3 * s1;
            op[2 * OW + 4] = s5 + v1 * s4 + v2 * s3 + v3 * s2;
            op[3 * OW + 4] = s6 + v1 * s5 + v2 * s4 + v3 * s3;
        }

        // Output row 256 (only group 7, wave 7): H[256]=H[257]=0.
        if (rg == 7 && wv == 7) {
            float4 Hm2 = *(const float4*)(Hs + 32 * HSTR + c0);  // H[254]
            float4 Hm1 = *(const float4*)(Hs + 33 * HSTR + c0);  // H[255]
            float4 R;
            R.x = v2 * Hm1.x + v3 * Hm2.x;
            R.y = v2 * Hm1.y + v3 * Hm2.y;
            R.z = v2 * Hm1.z + v3 * Hm2.z;
            R.w = v2 * Hm1.w + v3 * Hm2.w;
            *(f4u*)(op + 4 * OW) = (f4u){R.x, R.y, R.z, R.w};
            if (last)
                op[4 * OW + 4] = v2 * Hs[33 * HSTR + 256] + v3 * Hs[32 * HSTR + 256];
        }
    }
}

extern "C" void kernel_launch(void* const* d_in, const int* in_sizes, int n_in,
                              void* d_out, int out_size, void* d_ws, size_t ws_size,
                              hipStream_t stream) {
    const float* x   = (const float*)d_in[0];
    const float* k2d = (const float*)d_in[1];
    float* out = (float*)d_out;

    int nplanes = in_sizes[0] >> 16;               // B*C = 2048
    int ntasks  = nplanes * 8;                     // 16384 32-row group tasks
    int nblocks = 1024;                            // 8192 waves, 16 tasks/block

    blur_fir_kernel<<<nblocks, 512, 0, stream>>>(x, k2d, out, ntasks, nblocks);
}